// Round 13
// baseline (670.056 us; speedup 1.0000x reference)
//
#include <hip/hip_runtime.h>
#include <hip/hip_bf16.h>

// Problem constants
#define BB    4
#define CIN_  64
#define RIN_  6
#define CH_   5
#define HH    64
#define WW_   128
#define KD    384
#define MD    384
#define PH    66
#define PW    130
#define PSZ   (PH*PW)

#define NTAP 7
#define WEXP2_ELEMS (NTAP*MD*KD)
#define WEXP2_BYTES (WEXP2_ELEMS*2)

// fused prep grid layout
#define NB_INTERIOR 7680                 // 20 bc x 64 y x 2 xh x 3 kblk
#define NB_BORDER   380                  // 20 bc x 19 (4656 idx / 256)
#define NB_WEXP     4032                 // 1,032,192 / 256
#define NB_PREP     (NB_INTERIOR + NB_BORDER + NB_WEXP)

typedef __hip_bfloat16 bf16;
typedef __attribute__((ext_vector_type(8))) short bf16x8;
typedef __attribute__((ext_vector_type(4))) float f32x4;

__device__ const int TMAP[NTAP] = {0,1,3,4,5,7,8};
__device__ const int IDXK[6][9] = {
    {5,4,6,6,0,3,6,1,2},
    {4,3,6,5,0,2,6,6,1},
    {3,2,6,4,0,1,6,5,6},
    {2,1,6,3,0,6,6,4,5},
    {1,6,6,2,0,5,6,3,4},
    {6,5,6,1,0,4,6,2,3},
};

// -------- fused prep kernel: interior pad + border gather + weight expand
// (unchanged from Round 12 — verified)
__global__ __launch_bounds__(256) void prep_kernel(const float* __restrict__ x,
                                                   const float* __restrict__ w,
                                                   bf16* __restrict__ P,
                                                   bf16* __restrict__ W2) {
    const int blk = blockIdx.x;
    const int tid = threadIdx.x;

    if (blk < NB_INTERIOR) {
        int bid  = blk;
        int kblk = bid % 3;
        int xh   = (bid / 3) & 1;
        int y    = (bid / 6) % 64;
        int bc   = bid / 384;
        int c = bc % 5, b = bc / 5;

        int lane = tid & 63;
        int wv   = tid >> 6;
        int k0   = kblk * 128 + wv * 32;
        int sx   = xh * 64 + lane;
        int xx   = sx + 1;

        bool mask0 = (y == 0 && sx == 127) || (y == 63 && sx == 0);

        const float* src = x + ((((size_t)(b * 384 + k0) * 5 + c) * 64 + y) * 128 + sx);
        unsigned int hbuf[16];
        #pragma unroll
        for (int kk = 0; kk < 32; kk += 2) {
            float v1 = src[(size_t)kk * 40960];
            float v2 = src[(size_t)(kk + 1) * 40960];
            if (mask0) { v1 = 0.f; v2 = 0.f; }
            bf16 h1 = __float2bfloat16(v1);
            bf16 h2 = __float2bfloat16(v2);
            hbuf[kk >> 1] = ((unsigned int)*(unsigned short*)&h2 << 16) |
                            (unsigned int)*(unsigned short*)&h1;
        }
        bf16* dst = P + (((size_t)(b * 5 + c) * PH + (y + 1)) * PW + xx) * KD + k0;
        uint4* d4 = (uint4*)dst;
        #pragma unroll
        for (int q = 0; q < 4; ++q)
            d4[q] = make_uint4(hbuf[4*q], hbuf[4*q+1], hbuf[4*q+2], hbuf[4*q+3]);
        return;
    }

    if (blk < NB_INTERIOR + NB_BORDER) {
        int bidB = blk - NB_INTERIOR;
        int bc   = bidB / 19;
        int idx  = (bidB % 19) * 256 + tid;
        if (idx >= 12 * 388) return;
        int c = bc % 5, b = bc / 5;
        int chunk = idx / 388;          // 0..11 (32 k each)
        int p     = idx % 388;

        int yy, xx;
        if (p < 130)      { yy = 0;  xx = p; }
        else if (p < 260) { yy = 65; xx = p - 130; }
        else if (p < 324) { yy = 1 + (p - 260); xx = 0; }
        else              { yy = 1 + (p - 324); xx = 129; }

        int dr = 0, sc = c, sy = 0, sx = 0;
        bool zi = false;
        if (xx == 129) {
            if (yy >= 2) { dr = 5; sc = (c + 1) % 5; sy = 0; sx = 129 - yy; }
            else zi = true;
        } else if (yy == 0) {
            if (xx >= 1 && xx <= 64)        { dr = 0; sc = (c + 4) % 5; sy = 63; sx = 63 + xx; }
            else if (xx >= 65 && xx <= 128) { dr = 1; sc = (c + 4) % 5; sy = 128 - xx; sx = 127; }
            else zi = true;
        } else if (yy == 65) {
            if (xx >= 65 && xx <= 128)      { dr = 0; sc = (c + 1) % 5; sy = 0; sx = xx - 65; }
            else if (xx >= 2 && xx <= 64)   { dr = 1; sc = (c + 1) % 5; sy = 65 - xx; sx = 0; }
            else zi = true;
        } else { // xx==0, yy in [1,64]
            dr = 5; sc = (c + 4) % 5; sy = 63; sx = 64 - yy;
        }
        if (zi) { dr = 0; sc = 0; sy = 0; sx = 0; }
        bool kill = !zi && ((sy == 0 && sx == 127) || (sy == 63 && sx == 0));

        const size_t SBASE = ((size_t)(b * 1920 + sc)) * 8192 + sy * 128 + sx;
        const int k0 = chunk * 32;

        unsigned int hb[16];
        #pragma unroll
        for (int kk = 0; kk < 32; ++kk) {
            int k  = k0 + kk;
            int ci = k / 6;
            int r  = k - 6 * ci;
            int sr = zi ? 0 : ((r + dr >= 6) ? r + dr - 6 : r + dr);
            float v = x[SBASE + (size_t)(ci * 6 + sr) * 40960];
            if (kill) v = 0.f;
            bf16 h = __float2bfloat16(v);
            unsigned int hu = (unsigned int)*(unsigned short*)&h;
            if (kk & 1) hb[kk >> 1] |= hu << 16;
            else        hb[kk >> 1]  = hu;
        }
        bf16* dst = P + (((size_t)(b * 5 + c) * PH + yy) * PW + xx) * KD + k0;
        uint4* d4 = (uint4*)dst;
        #pragma unroll
        for (int q = 0; q < 4; ++q)
            d4[q] = make_uint4(hb[4*q], hb[4*q+1], hb[4*q+2], hb[4*q+3]);
        return;
    }

    {
        int e = (blk - NB_INTERIOR - NB_BORDER) * 256 + tid;
        if (e >= WEXP2_ELEMS) return;
        int k  = e % KD;
        int m  = (e / KD) % MD;
        int tt = e / (KD * MD);
        int t  = TMAP[tt];
        int co = m / 6, ro = m % 6, ci = k / 6, ri = k % 6;
        int rw = (ri - ro + 6) % 6;
        int s  = IDXK[ro][t];
        W2[e] = __float2bfloat16(w[((co * CIN_ + ci) * RIN_ + rw) * 7 + s]);
    }
}

// -------- kernel 3: implicit-GEMM conv, FREE-RUNNING WAVES (no K-loop barriers)
// 8 waves/block (512 thr); wave-tile 64m x 64n (acc 4x4 frags).
// Block output tile = 128m x 256n (2 y-rows x 128 x) — same as R8, grid unchanged.
// Each wave owns a PRIVATE 16 KB LDS region (2 bufs x {A 4KB + B 4KB}); it stages
// its own data (4+4 GLD/chunk) and reads only its own region (8 ds_read_b128).
// Sync: per-wave vmcnt(0) once per chunk; compiler-counted lgkmcnt for ds->MFMA.
// Zero cross-wave sharing => zero barriers => waves drift phases and keep both
// the LDS and MFMA pipes fed.
#define DYP 0x2950   // packed dy per tap: 0,0,1,1,1,2,2
#define DXP 0x2644   // packed dx per tap: 0,1,0,1,2,1,2

#define GLD(g, l) __builtin_amdgcn_global_load_lds( \
    (const __attribute__((address_space(1))) void*)(g), \
    (__attribute__((address_space(3))) void*)(l), 16, 0, 0)
#define MFMA_(a, b, c) __builtin_amdgcn_mfma_f32_16x16x32_bf16((a), (b), (c), 0, 0, 0)

__global__ __launch_bounds__(512, 2) void conv_free(
        const bf16* __restrict__ P, const bf16* __restrict__ W2,
        const float* __restrict__ bias, float* __restrict__ out) {
    // 8 waves x 8192 elems (16 KB): [buf 0/1][A 2048 elems | B 2048 elems]
    __shared__ __align__(16) bf16 Ss[65536];   // 128 KB

    const int bid = blockIdx.x;
    const int w   = (bid & 7) * 240 + (bid >> 3);   // XCD swizzle, 1920 = 8*240
    const int mblk  = w % 3;
    const int ntile = (w / 3) % 32;
    const int bc    = w / 96;
    const int c = bc % 5, b = bc / 5;
    const int y0 = ntile * 2;

    const int tid  = threadIdx.x;
    const int lane = tid & 63;
    const int wv   = tid >> 6;          // 0..7
    const int wm   = wv >> 2;           // m-half: 64 m
    const int wn   = wv & 3;            // n-quarter: row y0+(wn>>1), cols (wn&1)*64
    const int lm   = lane & 15, lg = lane >> 4;

    const int mA0 = mblk * 128 + wm * 64;
    const int ry  = y0 + (wn >> 1);
    const int cx  = (wn & 1) * 64;

    const bf16* Pslice = P + (size_t)(b * 5 + c) * PSZ * KD;

    // GLD source bases (pre-swizzled; 4 rounds each of 64 lanes x 16B)
    const bf16* gA[4];
    const bf16* gB[4];
    #pragma unroll
    for (int q = 0; q < 4; ++q) {
        int s = q * 64 + lane;
        int row = s >> 2, kg = s & 3;
        gA[q] = W2 + (size_t)(mA0 + row) * KD + ((kg ^ ((row >> 1) & 3)) << 3);
        gB[q] = Pslice + (size_t)row * KD + ((kg ^ ((row >> 1) & 3)) << 3);  // row==col here
    }

    // ds-read byte offsets within the wave's region (same verified swizzle)
    const int wvByte = wv * 16384;           // wave base (bytes)
    int oA[4], oB[4];
    #pragma unroll
    for (int i = 0; i < 4; ++i) {
        int mm = i * 16 + lm;                // local m row 0..63
        oA[i] = (mm * 4 + (lg ^ ((mm >> 1) & 3))) * 16;
        oB[i] = (mm * 4 + (lg ^ ((mm >> 1) & 3))) * 16 + 4096;  // B region at +4KB
    }
    const char* Sb = (const char*)&Ss[0];

    // LDS dest bases (wave-uniform + lane*16 implicit)
    // buf n at wvByte + n*8192; A rounds at +q*1024; B rounds at +4096+q*1024.

    f32x4 acc[4][4] = {};

    // prologue: stage chunk 0 (tap 0: dy=0, dx=0; skc=0) into buf 0
    {
        size_t offB = ((size_t)ry * PW + cx) * KD;
        #pragma unroll
        for (int q = 0; q < 4; ++q)
            GLD(gA[q], (char*)&Ss[0] + wvByte + q * 1024);
        #pragma unroll
        for (int q = 0; q < 4; ++q)
            GLD(gB[q] + offB, (char*)&Ss[0] + wvByte + 4096 + q * 1024);
    }
    asm volatile("s_waitcnt vmcnt(0)" ::: "memory");

    #pragma unroll 1
    for (int ch = 0; ch < 84; ++ch) {
        const int bufB = (ch & 1) * 8192;        // current buf byte offset

        // ---- prefetch chunk ch+1 into the other buffer (8 GLD, per-wave private)
        if (ch < 83) {
            int nch = ch + 1;
            int stt = nch / 12;                  // tap
            int skc = nch - stt * 12;            // k-chunk
            int dy  = (DYP >> (2 * stt)) & 3;
            int dx  = (DXP >> (2 * stt)) & 3;
            size_t offA = (size_t)stt * (MD * KD) + skc * 32;
            size_t offB = ((size_t)(ry + dy) * PW + dx + cx) * KD + skc * 32;
            const int nb = ((ch + 1) & 1) * 8192;
            #pragma unroll
            for (int q = 0; q < 4; ++q)
                GLD(gA[q] + offA, (char*)&Ss[0] + wvByte + nb + q * 1024);
            #pragma unroll
            for (int q = 0; q < 4; ++q)
                GLD(gB[q] + offB, (char*)&Ss[0] + wvByte + nb + 4096 + q * 1024);
        }

        // ---- ds_read this wave's 8 fragments of chunk ch
        bf16x8 a0 = *(const bf16x8*)(Sb + wvByte + bufB + oA[0]);
        bf16x8 a1 = *(const bf16x8*)(Sb + wvByte + bufB + oA[1]);
        bf16x8 a2 = *(const bf16x8*)(Sb + wvByte + bufB + oA[2]);
        bf16x8 a3 = *(const bf16x8*)(Sb + wvByte + bufB + oA[3]);
        bf16x8 b0 = *(const bf16x8*)(Sb + wvByte + bufB + oB[0]);
        bf16x8 b1 = *(const bf16x8*)(Sb + wvByte + bufB + oB[1]);
        bf16x8 b2 = *(const bf16x8*)(Sb + wvByte + bufB + oB[2]);
        bf16x8 b3 = *(const bf16x8*)(Sb + wvByte + bufB + oB[3]);

        // ---- 16 MFMA (compiler inserts counted lgkmcnt before first uses)
        __builtin_amdgcn_s_setprio(1);
        acc[0][0] = MFMA_(a0, b0, acc[0][0]);
        acc[1][0] = MFMA_(a1, b0, acc[1][0]);
        acc[2][0] = MFMA_(a2, b0, acc[2][0]);
        acc[3][0] = MFMA_(a3, b0, acc[3][0]);
        acc[0][1] = MFMA_(a0, b1, acc[0][1]);
        acc[1][1] = MFMA_(a1, b1, acc[1][1]);
        acc[2][1] = MFMA_(a2, b1, acc[2][1]);
        acc[3][1] = MFMA_(a3, b1, acc[3][1]);
        acc[0][2] = MFMA_(a0, b2, acc[0][2]);
        acc[1][2] = MFMA_(a1, b2, acc[1][2]);
        acc[2][2] = MFMA_(a2, b2, acc[2][2]);
        acc[3][2] = MFMA_(a3, b2, acc[3][2]);
        acc[0][3] = MFMA_(a0, b3, acc[0][3]);
        acc[1][3] = MFMA_(a1, b3, acc[1][3]);
        acc[2][3] = MFMA_(a2, b3, acc[2][3]);
        acc[3][3] = MFMA_(a3, b3, acc[3][3]);
        __builtin_amdgcn_s_setprio(0);

        // ---- per-wave wait: next chunk's 8 GLDs must have landed before its
        // ds_reads (next iteration). No barrier — other waves keep running.
        if (ch < 83)
            asm volatile("s_waitcnt vmcnt(0)" ::: "memory");
    }

    // epilogue: bias + VMASK + store
    #pragma unroll
    for (int i = 0; i < 4; ++i) {
        #pragma unroll
        for (int r = 0; r < 4; ++r) {
            int m = mA0 + i * 16 + lg * 4 + r;
            float bv = bias[m / 6];
            #pragma unroll
            for (int j = 0; j < 4; ++j) {
                int xq = cx + j * 16 + lm;
                float v = acc[i][j][r] + bv;
                if ((ry == 0 && xq == 127) || (ry == 63 && xq == 0)) v = 0.f;
                out[((size_t)(b * MD + m) * CH_ + c) * (HH * WW_) + ry * WW_ + xq] = v;
            }
        }
    }
}

extern "C" void kernel_launch(void* const* d_in, const int* in_sizes, int n_in,
                              void* d_out, int out_size, void* d_ws, size_t ws_size,
                              hipStream_t stream) {
    const float* x    = (const float*)d_in[0];
    const float* w    = (const float*)d_in[1];
    const float* bias = (const float*)d_in[2];
    float* out        = (float*)d_out;

    bf16* W2 = (bf16*)d_ws;
    bf16* P  = (bf16*)((char*)d_ws + WEXP2_BYTES);

    // one fused prep launch: interior pad + border gather + weight expand
    prep_kernel<<<NB_PREP, 256, 0, stream>>>(x, w, P, W2);

    // grid: 3 m-blocks x 32 n-tiles x 20 (b,c) = 1920 blocks, 512 threads
    conv_free<<<1920, 512, 0, stream>>>(P, W2, bias, out);
}

// Round 14
// 668.950 us; speedup vs baseline: 1.0017x; 1.0017x over previous
//
#include <hip/hip_runtime.h>
#include <hip/hip_bf16.h>

// Problem constants
#define BB    4
#define CIN_  64
#define RIN_  6
#define CH_   5
#define HH    64
#define WW_   128
#define KD    384
#define MD    384
#define PH    66
#define PW    130
#define PSZ   (PH*PW)

#define NTAP 7
#define WEXP2_ELEMS (NTAP*MD*KD)
#define WEXP2_BYTES (WEXP2_ELEMS*2)

// fused prep grid layout
#define NB_INTERIOR 7680                 // 20 bc x 64 y x 2 xh x 3 kblk
#define NB_BORDER   380                  // 20 bc x 19 (4656 idx / 256)
#define NB_WEXP     4032                 // 1,032,192 / 256
#define NB_PREP     (NB_INTERIOR + NB_BORDER + NB_WEXP)

typedef __hip_bfloat16 bf16;
typedef __attribute__((ext_vector_type(8))) short bf16x8;
typedef __attribute__((ext_vector_type(4))) float f32x4;

__device__ const int TMAP[NTAP] = {0,1,3,4,5,7,8};
__device__ const int IDXK[6][9] = {
    {5,4,6,6,0,3,6,1,2},
    {4,3,6,5,0,2,6,6,1},
    {3,2,6,4,0,1,6,5,6},
    {2,1,6,3,0,6,6,4,5},
    {1,6,6,2,0,5,6,3,4},
    {6,5,6,1,0,4,6,2,3},
};

// -------- fused prep kernel: interior pad + border gather + weight expand
// (unchanged from Round 12 — verified)
__global__ __launch_bounds__(256) void prep_kernel(const float* __restrict__ x,
                                                   const float* __restrict__ w,
                                                   bf16* __restrict__ P,
                                                   bf16* __restrict__ W2) {
    const int blk = blockIdx.x;
    const int tid = threadIdx.x;

    if (blk < NB_INTERIOR) {
        int bid  = blk;
        int kblk = bid % 3;
        int xh   = (bid / 3) & 1;
        int y    = (bid / 6) % 64;
        int bc   = bid / 384;
        int c = bc % 5, b = bc / 5;

        int lane = tid & 63;
        int wv   = tid >> 6;
        int k0   = kblk * 128 + wv * 32;
        int sx   = xh * 64 + lane;
        int xx   = sx + 1;

        bool mask0 = (y == 0 && sx == 127) || (y == 63 && sx == 0);

        const float* src = x + ((((size_t)(b * 384 + k0) * 5 + c) * 64 + y) * 128 + sx);
        unsigned int hbuf[16];
        #pragma unroll
        for (int kk = 0; kk < 32; kk += 2) {
            float v1 = src[(size_t)kk * 40960];
            float v2 = src[(size_t)(kk + 1) * 40960];
            if (mask0) { v1 = 0.f; v2 = 0.f; }
            bf16 h1 = __float2bfloat16(v1);
            bf16 h2 = __float2bfloat16(v2);
            hbuf[kk >> 1] = ((unsigned int)*(unsigned short*)&h2 << 16) |
                            (unsigned int)*(unsigned short*)&h1;
        }
        bf16* dst = P + (((size_t)(b * 5 + c) * PH + (y + 1)) * PW + xx) * KD + k0;
        uint4* d4 = (uint4*)dst;
        #pragma unroll
        for (int q = 0; q < 4; ++q)
            d4[q] = make_uint4(hbuf[4*q], hbuf[4*q+1], hbuf[4*q+2], hbuf[4*q+3]);
        return;
    }

    if (blk < NB_INTERIOR + NB_BORDER) {
        int bidB = blk - NB_INTERIOR;
        int bc   = bidB / 19;
        int idx  = (bidB % 19) * 256 + tid;
        if (idx >= 12 * 388) return;
        int c = bc % 5, b = bc / 5;
        int chunk = idx / 388;          // 0..11 (32 k each)
        int p     = idx % 388;

        int yy, xx;
        if (p < 130)      { yy = 0;  xx = p; }
        else if (p < 260) { yy = 65; xx = p - 130; }
        else if (p < 324) { yy = 1 + (p - 260); xx = 0; }
        else              { yy = 1 + (p - 324); xx = 129; }

        int dr = 0, sc = c, sy = 0, sx = 0;
        bool zi = false;
        if (xx == 129) {
            if (yy >= 2) { dr = 5; sc = (c + 1) % 5; sy = 0; sx = 129 - yy; }
            else zi = true;
        } else if (yy == 0) {
            if (xx >= 1 && xx <= 64)        { dr = 0; sc = (c + 4) % 5; sy = 63; sx = 63 + xx; }
            else if (xx >= 65 && xx <= 128) { dr = 1; sc = (c + 4) % 5; sy = 128 - xx; sx = 127; }
            else zi = true;
        } else if (yy == 65) {
            if (xx >= 65 && xx <= 128)      { dr = 0; sc = (c + 1) % 5; sy = 0; sx = xx - 65; }
            else if (xx >= 2 && xx <= 64)   { dr = 1; sc = (c + 1) % 5; sy = 65 - xx; sx = 0; }
            else zi = true;
        } else { // xx==0, yy in [1,64]
            dr = 5; sc = (c + 4) % 5; sy = 63; sx = 64 - yy;
        }
        if (zi) { dr = 0; sc = 0; sy = 0; sx = 0; }
        bool kill = !zi && ((sy == 0 && sx == 127) || (sy == 63 && sx == 0));

        const size_t SBASE = ((size_t)(b * 1920 + sc)) * 8192 + sy * 128 + sx;
        const int k0 = chunk * 32;

        unsigned int hb[16];
        #pragma unroll
        for (int kk = 0; kk < 32; ++kk) {
            int k  = k0 + kk;
            int ci = k / 6;
            int r  = k - 6 * ci;
            int sr = zi ? 0 : ((r + dr >= 6) ? r + dr - 6 : r + dr);
            float v = x[SBASE + (size_t)(ci * 6 + sr) * 40960];
            if (kill) v = 0.f;
            bf16 h = __float2bfloat16(v);
            unsigned int hu = (unsigned int)*(unsigned short*)&h;
            if (kk & 1) hb[kk >> 1] |= hu << 16;
            else        hb[kk >> 1]  = hu;
        }
        bf16* dst = P + (((size_t)(b * 5 + c) * PH + yy) * PW + xx) * KD + k0;
        uint4* d4 = (uint4*)dst;
        #pragma unroll
        for (int q = 0; q < 4; ++q)
            d4[q] = make_uint4(hb[4*q], hb[4*q+1], hb[4*q+2], hb[4*q+3]);
        return;
    }

    {
        int e = (blk - NB_INTERIOR - NB_BORDER) * 256 + tid;
        if (e >= WEXP2_ELEMS) return;
        int k  = e % KD;
        int m  = (e / KD) % MD;
        int tt = e / (KD * MD);
        int t  = TMAP[tt];
        int co = m / 6, ro = m % 6, ci = k / 6, ri = k % 6;
        int rw = (ri - ro + 6) % 6;
        int s  = IDXK[ro][t];
        W2[e] = __float2bfloat16(w[((co * CIN_ + ci) * RIN_ + rw) * 7 + s]);
    }
}

// -------- kernel 3: implicit-GEMM conv, FREE-RUNNING WAVES (no K-loop barriers)
// 8 waves/block (512 thr); wave-tile 64m x 64n (acc 4x4 frags).
// Block output tile = 128m x 256n (2 y-rows x 128 x) — same as R8, grid unchanged.
// Each wave owns a PRIVATE 16 KB LDS region (2 bufs x {A 4KB + B 4KB}); it stages
// its own data (4+4 GLD/chunk) and reads only its own region (8 ds_read_b128).
// Sync: per-wave vmcnt(0) once per chunk; compiler-counted lgkmcnt for ds->MFMA.
// Zero cross-wave sharing => zero barriers => waves drift phases and keep both
// the LDS and MFMA pipes fed.
#define DYP 0x2950   // packed dy per tap: 0,0,1,1,1,2,2
#define DXP 0x2644   // packed dx per tap: 0,1,0,1,2,1,2

#define GLD(g, l) __builtin_amdgcn_global_load_lds( \
    (const __attribute__((address_space(1))) void*)(g), \
    (__attribute__((address_space(3))) void*)(l), 16, 0, 0)
#define MFMA_(a, b, c) __builtin_amdgcn_mfma_f32_16x16x32_bf16((a), (b), (c), 0, 0, 0)

__global__ __launch_bounds__(512, 2) void conv_free(
        const bf16* __restrict__ P, const bf16* __restrict__ W2,
        const float* __restrict__ bias, float* __restrict__ out) {
    // 8 waves x 8192 elems (16 KB): [buf 0/1][A 2048 elems | B 2048 elems]
    __shared__ __align__(16) bf16 Ss[65536];   // 128 KB

    const int bid = blockIdx.x;
    const int w   = (bid & 7) * 240 + (bid >> 3);   // XCD swizzle, 1920 = 8*240
    const int mblk  = w % 3;
    const int ntile = (w / 3) % 32;
    const int bc    = w / 96;
    const int c = bc % 5, b = bc / 5;
    const int y0 = ntile * 2;

    const int tid  = threadIdx.x;
    const int lane = tid & 63;
    const int wv   = tid >> 6;          // 0..7
    const int wm   = wv >> 2;           // m-half: 64 m
    const int wn   = wv & 3;            // n-quarter: row y0+(wn>>1), cols (wn&1)*64
    const int lm   = lane & 15, lg = lane >> 4;

    const int mA0 = mblk * 128 + wm * 64;
    const int ry  = y0 + (wn >> 1);
    const int cx  = (wn & 1) * 64;

    const bf16* Pslice = P + (size_t)(b * 5 + c) * PSZ * KD;

    // GLD source bases (pre-swizzled; 4 rounds each of 64 lanes x 16B)
    const bf16* gA[4];
    const bf16* gB[4];
    #pragma unroll
    for (int q = 0; q < 4; ++q) {
        int s = q * 64 + lane;
        int row = s >> 2, kg = s & 3;
        gA[q] = W2 + (size_t)(mA0 + row) * KD + ((kg ^ ((row >> 1) & 3)) << 3);
        gB[q] = Pslice + (size_t)row * KD + ((kg ^ ((row >> 1) & 3)) << 3);  // row==col here
    }

    // ds-read byte offsets within the wave's region (same verified swizzle)
    const int wvByte = wv * 16384;           // wave base (bytes)
    int oA[4], oB[4];
    #pragma unroll
    for (int i = 0; i < 4; ++i) {
        int mm = i * 16 + lm;                // local m row 0..63
        oA[i] = (mm * 4 + (lg ^ ((mm >> 1) & 3))) * 16;
        oB[i] = (mm * 4 + (lg ^ ((mm >> 1) & 3))) * 16 + 4096;  // B region at +4KB
    }
    const char* Sb = (const char*)&Ss[0];

    // LDS dest bases (wave-uniform + lane*16 implicit)
    // buf n at wvByte + n*8192; A rounds at +q*1024; B rounds at +4096+q*1024.

    f32x4 acc[4][4] = {};

    // prologue: stage chunk 0 (tap 0: dy=0, dx=0; skc=0) into buf 0
    {
        size_t offB = ((size_t)ry * PW + cx) * KD;
        #pragma unroll
        for (int q = 0; q < 4; ++q)
            GLD(gA[q], (char*)&Ss[0] + wvByte + q * 1024);
        #pragma unroll
        for (int q = 0; q < 4; ++q)
            GLD(gB[q] + offB, (char*)&Ss[0] + wvByte + 4096 + q * 1024);
    }
    asm volatile("s_waitcnt vmcnt(0)" ::: "memory");

    #pragma unroll 1
    for (int ch = 0; ch < 84; ++ch) {
        const int bufB = (ch & 1) * 8192;        // current buf byte offset

        // ---- prefetch chunk ch+1 into the other buffer (8 GLD, per-wave private)
        if (ch < 83) {
            int nch = ch + 1;
            int stt = nch / 12;                  // tap
            int skc = nch - stt * 12;            // k-chunk
            int dy  = (DYP >> (2 * stt)) & 3;
            int dx  = (DXP >> (2 * stt)) & 3;
            size_t offA = (size_t)stt * (MD * KD) + skc * 32;
            size_t offB = ((size_t)(ry + dy) * PW + dx + cx) * KD + skc * 32;
            const int nb = ((ch + 1) & 1) * 8192;
            #pragma unroll
            for (int q = 0; q < 4; ++q)
                GLD(gA[q] + offA, (char*)&Ss[0] + wvByte + nb + q * 1024);
            #pragma unroll
            for (int q = 0; q < 4; ++q)
                GLD(gB[q] + offB, (char*)&Ss[0] + wvByte + nb + 4096 + q * 1024);
        }

        // ---- ds_read this wave's 8 fragments of chunk ch
        bf16x8 a0 = *(const bf16x8*)(Sb + wvByte + bufB + oA[0]);
        bf16x8 a1 = *(const bf16x8*)(Sb + wvByte + bufB + oA[1]);
        bf16x8 a2 = *(const bf16x8*)(Sb + wvByte + bufB + oA[2]);
        bf16x8 a3 = *(const bf16x8*)(Sb + wvByte + bufB + oA[3]);
        bf16x8 b0 = *(const bf16x8*)(Sb + wvByte + bufB + oB[0]);
        bf16x8 b1 = *(const bf16x8*)(Sb + wvByte + bufB + oB[1]);
        bf16x8 b2 = *(const bf16x8*)(Sb + wvByte + bufB + oB[2]);
        bf16x8 b3 = *(const bf16x8*)(Sb + wvByte + bufB + oB[3]);

        // ---- 16 MFMA (compiler inserts counted lgkmcnt before first uses)
        __builtin_amdgcn_s_setprio(1);
        acc[0][0] = MFMA_(a0, b0, acc[0][0]);
        acc[1][0] = MFMA_(a1, b0, acc[1][0]);
        acc[2][0] = MFMA_(a2, b0, acc[2][0]);
        acc[3][0] = MFMA_(a3, b0, acc[3][0]);
        acc[0][1] = MFMA_(a0, b1, acc[0][1]);
        acc[1][1] = MFMA_(a1, b1, acc[1][1]);
        acc[2][1] = MFMA_(a2, b1, acc[2][1]);
        acc[3][1] = MFMA_(a3, b1, acc[3][1]);
        acc[0][2] = MFMA_(a0, b2, acc[0][2]);
        acc[1][2] = MFMA_(a1, b2, acc[1][2]);
        acc[2][2] = MFMA_(a2, b2, acc[2][2]);
        acc[3][2] = MFMA_(a3, b2, acc[3][2]);
        acc[0][3] = MFMA_(a0, b3, acc[0][3]);
        acc[1][3] = MFMA_(a1, b3, acc[1][3]);
        acc[2][3] = MFMA_(a2, b3, acc[2][3]);
        acc[3][3] = MFMA_(a3, b3, acc[3][3]);
        __builtin_amdgcn_s_setprio(0);

        // ---- per-wave wait: next chunk's 8 GLDs must have landed before its
        // ds_reads (next iteration). No barrier — other waves keep running.
        if (ch < 83)
            asm volatile("s_waitcnt vmcnt(0)" ::: "memory");
    }

    // epilogue: bias + VMASK + store
    #pragma unroll
    for (int i = 0; i < 4; ++i) {
        #pragma unroll
        for (int r = 0; r < 4; ++r) {
            int m = mA0 + i * 16 + lg * 4 + r;
            float bv = bias[m / 6];
            #pragma unroll
            for (int j = 0; j < 4; ++j) {
                int xq = cx + j * 16 + lm;
                float v = acc[i][j][r] + bv;
                if ((ry == 0 && xq == 127) || (ry == 63 && xq == 0)) v = 0.f;
                out[((size_t)(b * MD + m) * CH_ + c) * (HH * WW_) + ry * WW_ + xq] = v;
            }
        }
    }
}

extern "C" void kernel_launch(void* const* d_in, const int* in_sizes, int n_in,
                              void* d_out, int out_size, void* d_ws, size_t ws_size,
                              hipStream_t stream) {
    const float* x    = (const float*)d_in[0];
    const float* w    = (const float*)d_in[1];
    const float* bias = (const float*)d_in[2];
    float* out        = (float*)d_out;

    bf16* W2 = (bf16*)d_ws;
    bf16* P  = (bf16*)((char*)d_ws + WEXP2_BYTES);

    // one fused prep launch: interior pad + border gather + weight expand
    prep_kernel<<<NB_PREP, 256, 0, stream>>>(x, w, P, W2);

    // grid: 3 m-blocks x 32 n-tiles x 20 (b,c) = 1920 blocks, 512 threads
    conv_free<<<1920, 512, 0, stream>>>(P, W2, bias, out);
}